// Round 8
// baseline (134.070 us; speedup 1.0000x reference)
//
#include <hip/hip_runtime.h>
#include <hip/hip_bf16.h>

// B=32, H=W=96, D=128, WS=6, SS=3.
// tok layout: [set(2)][b(32)][wy(16)][wx(16)][d(128)] = 8 MB in d_ws.
// k_wintok: window means via 3x3-tile sums + fused token_proj.
// k_fuse_out: fuse + out_proj on the 3x3-distinct vectors + expand.
// GEMM weights are staged in 32 KB LDS half-panels shared by all 8 waves
// (one L2 read per block, LDS-latency k-loop) — NOT per-wave L2 streaming
// (round-7 latency bottleneck) and NOT full-W LDS (round-5 occupancy kill).

#define DEVFN static __device__ __forceinline__

DEVFN float gelu_exact(float x) {
  return 0.5f * x * (1.0f + erff(x * 0.70710678118654752f));
}

DEVFN void add4(float4& a, const float4 v) {
  a.x += v.x; a.y += v.y; a.z += v.z; a.w += v.w;
}
DEVFN void fma4(float4& a, const float4 v, float m) {
  a.x = fmaf(v.x, m, a.x); a.y = fmaf(v.y, m, a.y);
  a.z = fmaf(v.z, m, a.z); a.w = fmaf(v.w, m, a.w);
}

// Stage 64 k-rows of W (32 KB) into LDS panel; 512 threads x 4 float4.
DEVFN void stage_w(float (*wp)[128], const float* __restrict__ W, int krow0,
                   int tid) {
  const float4* src = reinterpret_cast<const float4*>(W + (size_t)krow0 * 128);
  #pragma unroll
  for (int i = 0; i < 4; ++i)
    reinterpret_cast<float4*>(&wp[0][0])[tid + i * 512] = src[tid + i * 512];
}

// Accumulate 64 k-rows (panel) into a0/a1; FMA order identical to the
// monolithic k-loop (k ascending, groups of 4) -> bit-identical results.
template <int T>
DEVFN void gemm_acc(const float (*wp)[128], const float (*xs)[128],
                    int kbase, int tb, int lane,
                    float (&a0)[T], float (&a1)[T]) {
  const int n0 = lane << 1;
  #pragma unroll 2
  for (int kk = 0; kk < 64; kk += 4) {
    const float2 w0 = *reinterpret_cast<const float2*>(&wp[kk + 0][n0]);
    const float2 w1 = *reinterpret_cast<const float2*>(&wp[kk + 1][n0]);
    const float2 w2 = *reinterpret_cast<const float2*>(&wp[kk + 2][n0]);
    const float2 w3 = *reinterpret_cast<const float2*>(&wp[kk + 3][n0]);
    #pragma unroll
    for (int t = 0; t < T; ++t) {
      const float4 xv =
          *reinterpret_cast<const float4*>(&xs[tb + t][kbase + kk]);
      a0[t] = fmaf(xv.x, w0.x, a0[t]); a1[t] = fmaf(xv.x, w0.y, a1[t]);
      a0[t] = fmaf(xv.y, w1.x, a0[t]); a1[t] = fmaf(xv.y, w1.y, a1[t]);
      a0[t] = fmaf(xv.z, w2.x, a0[t]); a1[t] = fmaf(xv.z, w2.y, a1[t]);
      a0[t] = fmaf(xv.w, w3.x, a0[t]); a1[t] = fmaf(xv.w, w3.y, a1[t]);
    }
  }
}

template <int T>
DEVFN void ln_gelu_finish(int lane, const float (&a0)[T], const float (&a1)[T],
                          const float* __restrict__ bias,
                          const float* __restrict__ gam,
                          const float* __restrict__ bet,
                          float (&o0)[T], float (&o1)[T]) {
  const int n0 = lane << 1;
  const float b0 = bias[n0], b1 = bias[n0 + 1];
  const float g0 = gam[n0],  g1 = gam[n0 + 1];
  const float e0 = bet[n0],  e1 = bet[n0 + 1];
  #pragma unroll
  for (int t = 0; t < T; ++t) {
    const float v0 = a0[t] + b0, v1 = a1[t] + b1;
    float s = v0 + v1, q = v0 * v0 + v1 * v1;
    #pragma unroll
    for (int m = 1; m < 64; m <<= 1) {
      s += __shfl_xor(s, m, 64);
      q += __shfl_xor(q, m, 64);
    }
    const float mean = s * (1.f / 128.f);
    const float var  = q * (1.f / 128.f) - mean * mean;
    const float inv  = rsqrtf(var + 1e-5f);
    o0[t] = gelu_exact((v0 - mean) * inv * g0 + e0);
    o1[t] = gelu_exact((v1 - mean) * inv * g1 + e1);
  }
}

// ------- Kernel 1: window means via 3x3-tile sums + fused token_proj -------
// grid = 32*16 (b, band r), 512 threads = 8 waves. Band rows 6r..6r+8 (mod 96)
// = tile-rows {2r,2r+1,2r+2}. Wave w owns cols [12w,12w+12) = tile-cols
// 4w..4w+3; float4 loads, masked-FMA for tile-straddling column pairs.
// reg win (r,wx) = tiles[0..1][2wx..2wx+1]; sh win = tiles[1..2][2wx+1..2wx+2&31].
// token_proj: xs aliases tiles[0]; Wt panel aliases tiles[1..2] (dead after
// compose) -> LDS stays 48 KB.
__global__ __launch_bounds__(512) void k_wintok(const float* __restrict__ h,
    const float* __restrict__ Wt, const float* __restrict__ bt,
    const float* __restrict__ gt, const float* __restrict__ bgt,
    float* __restrict__ tok) {
  __shared__ __align__(16) float tiles[3][32][128];
  const int b = blockIdx.x >> 4;
  const int r = blockIdx.x & 15;
  const int w    = threadIdx.x >> 6;      // wave 0..7
  const int lane = threadIdx.x & 63;
  const int half = lane >> 5;             // 0/1: which of the 2 cols per instr
  const int ch4  = (lane & 31) << 2;      // 4 channels per lane
  const float mlo = half ? 0.f : 1.f;
  const float mhi = 1.f - mlo;

  float4 acc[3][4];
  #pragma unroll
  for (int a = 0; a < 3; ++a)
    #pragma unroll
    for (int t = 0; t < 4; ++t) acc[a][t] = make_float4(0.f, 0.f, 0.f, 0.f);

  #pragma unroll
  for (int yl = 0; yl < 9; ++yl) {
    int y = 6 * r + yl; if (y >= 96) y -= 96;
    const int tr = yl / 3;                // static (unrolled)
    const float* rp =
        h + ((size_t)(b * 9216 + y * 96 + 12 * w + half) * 128 + ch4);
    #pragma unroll
    for (int j = 0; j < 6; ++j) {
      const float4 v = *reinterpret_cast<const float4*>(rp + j * 256);
      if (j == 0)      add4(acc[tr][0], v);
      else if (j == 2) add4(acc[tr][1], v);
      else if (j == 3) add4(acc[tr][2], v);
      else if (j == 5) add4(acc[tr][3], v);
      else if (j == 1) { fma4(acc[tr][0], v, mlo); fma4(acc[tr][1], v, mhi); }
      else             { fma4(acc[tr][2], v, mlo); fma4(acc[tr][3], v, mhi); }
    }
  }

  #pragma unroll
  for (int a = 0; a < 3; ++a)
    #pragma unroll
    for (int t = 0; t < 4; ++t) {
      float4 s = acc[a][t];
      s.x += __shfl_xor(s.x, 32, 64);
      s.y += __shfl_xor(s.y, 32, 64);
      s.z += __shfl_xor(s.z, 32, 64);
      s.w += __shfl_xor(s.w, 32, 64);
      if (half == 0)
        *reinterpret_cast<float4*>(&tiles[a][4 * w + t][ch4]) = s;
    }
  __syncthreads();

  // Compose 32 window means (16 reg + 16 sh) into registers (8 values/thread).
  float cv[8];
  #pragma unroll
  for (int j = 0; j < 8; ++j) {
    const int i = threadIdx.x + j * 512;   // 0..4095
    const int t = i >> 7, d = i & 127;
    if (t < 16) {
      const int wx = t;
      cv[j] = (tiles[0][2 * wx][d] + tiles[0][2 * wx + 1][d] +
               tiles[1][2 * wx][d] + tiles[1][2 * wx + 1][d]) * (1.f / 36.f);
    } else {
      const int wx = t - 16;
      const int cA = 2 * wx + 1, cB = (2 * wx + 2) & 31;
      cv[j] = (tiles[1][cA][d] + tiles[1][cB][d] +
               tiles[2][cA][d] + tiles[2][cB][d]) * (1.f / 36.f);
    }
  }
  __syncthreads();
  float (*xs)[128] = tiles[0];             // 32x128 fits tiles[0] exactly
  float (*wp)[128] = tiles[1];             // tiles[1..2] = contiguous 32 KB
  #pragma unroll
  for (int j = 0; j < 8; ++j) {
    const int i = threadIdx.x + j * 512;
    xs[i >> 7][i & 127] = cv[j];
  }
  stage_w(wp, Wt, 0, threadIdx.x);
  __syncthreads();

  // token_proj on the 32 tokens: 4 tokens per wave, W via LDS half-panels.
  const int tb = w * 4;
  float a0[4], a1[4];
  #pragma unroll
  for (int t = 0; t < 4; ++t) { a0[t] = 0.f; a1[t] = 0.f; }
  gemm_acc<4>(wp, xs, 0, tb, lane, a0, a1);
  __syncthreads();
  stage_w(wp, Wt, 64, threadIdx.x);
  __syncthreads();
  gemm_acc<4>(wp, xs, 64, tb, lane, a0, a1);
  float o0[4], o1[4];
  ln_gelu_finish<4>(lane, a0, a1, bt, gt, bgt, o0, o1);

  const int n0 = lane << 1;
  #pragma unroll
  for (int t = 0; t < 4; ++t) {
    const int tt = tb + t;                 // 0..31
    const int s = tt >> 4, wx = tt & 15;
    *reinterpret_cast<float2*>(tok + (size_t)s * 1048576 +
        ((size_t)b * 16 + r) * 2048 + (size_t)wx * 128 + n0) =
        make_float2(o0[t], o1[t]);
  }
}

// -------- Kernel 2: fuse + out_proj on 3x3-distinct vectors + expand --------
// 512 threads = 8 waves = 64 tokens/block; grid = 32*16 (b, m). LDS 64 KB
// (xs 32 + W half-panel 32) -> 2 blocks/CU. ctx writeback rows are
// wave-private (no barrier); barriers only guard wp restaging.
__global__ __launch_bounds__(512) void k_fuse_out(const float* __restrict__ tok,
    const float* __restrict__ Wf, const float* __restrict__ bfv,
    const float* __restrict__ gf, const float* __restrict__ bgf,
    const float* __restrict__ Wo, const float* __restrict__ bo,
    const float* __restrict__ go, const float* __restrict__ bgo,
    const float* __restrict__ mask, float* __restrict__ out) {
  __shared__ __align__(16) float xs[64][128];
  __shared__ __align__(16) float wp[64][128];
  const int b = blockIdx.x >> 4;
  const int m = blockIdx.x & 15;
  const float* tokR = tok + (size_t)b * 32768 + (size_t)m * 2048;  // reg row m
  const float* tokS = tok + 1048576 + (size_t)b * 32768;

  for (int i = threadIdx.x; i < 2048; i += 512) {
    const int t = i >> 5, d4 = (i & 31) << 2;
    const int gx = t & 31, gy = 2 * m + (t >> 5);
    const int wx  = gx >> 1;
    const int wxs = ((gx + 31) & 31) >> 1;
    const int wys = ((gy + 31) & 31) >> 1;
    const float4 vr = *reinterpret_cast<const float4*>(tokR + (size_t)wx * 128 + d4);
    const float4 vs = *reinterpret_cast<const float4*>(tokS + (size_t)(wys * 16 + wxs) * 128 + d4);
    *reinterpret_cast<float4*>(&xs[t][d4]) =
        make_float4(vr.x + vs.x, vr.y + vs.y, vr.z + vs.z, vr.w + vs.w);
  }
  stage_w(wp, Wf, 0, threadIdx.x);
  __syncthreads();

  const int lane = threadIdx.x & 63;
  const int tb = (threadIdx.x >> 6) * 8;
  const int n0 = lane << 1;

  // ---- fuse block ----
  float a0[8], a1[8];
  #pragma unroll
  for (int t = 0; t < 8; ++t) { a0[t] = 0.f; a1[t] = 0.f; }
  gemm_acc<8>(wp, xs, 0, tb, lane, a0, a1);
  __syncthreads();
  stage_w(wp, Wf, 64, threadIdx.x);
  __syncthreads();
  gemm_acc<8>(wp, xs, 64, tb, lane, a0, a1);
  float c0[8], c1[8];
  ln_gelu_finish<8>(lane, a0, a1, bfv, gf, bgf, c0, c1);

  #pragma unroll
  for (int t = 0; t < 8; ++t) {   // wave-private rows; no barrier needed
    xs[tb + t][n0] = c0[t];
    xs[tb + t][n0 + 1] = c1[t];
  }
  __syncthreads();                 // all waves done reading wp (Wf hi)
  stage_w(wp, Wo, 0, threadIdx.x);
  __syncthreads();

  // ---- out_proj block ----
  #pragma unroll
  for (int t = 0; t < 8; ++t) { a0[t] = 0.f; a1[t] = 0.f; }
  gemm_acc<8>(wp, xs, 0, tb, lane, a0, a1);
  __syncthreads();
  stage_w(wp, Wo, 64, threadIdx.x);
  __syncthreads();
  gemm_acc<8>(wp, xs, 64, tb, lane, a0, a1);
  float o0[8], o1[8];
  ln_gelu_finish<8>(lane, a0, a1, bo, go, bgo, o0, o1);

  #pragma unroll
  for (int t = 0; t < 8; ++t) {
    const int tt = tb + t;
    const int gx = tt & 31, gy = 2 * m + (tt >> 5);
    #pragma unroll
    for (int i = 0; i < 3; ++i) {
      const int y = 3 * gy + i;
      #pragma unroll
      for (int j = 0; j < 3; ++j) {
        const int x = 3 * gx + j;
        const size_t pix = (size_t)b * 9216 + (size_t)y * 96 + x;
        const float mv = mask[pix];
        *reinterpret_cast<float2*>(out + pix * 128 + n0) =
            make_float2(o0[t] * mv, o1[t] * mv);
      }
    }
  }
}

extern "C" void kernel_launch(void* const* d_in, const int* in_sizes, int n_in,
                              void* d_out, int out_size, void* d_ws, size_t ws_size,
                              hipStream_t stream) {
  (void)in_sizes; (void)n_in; (void)out_size; (void)ws_size;
  const float* h    = (const float*)d_in[0];
  const float* mask = (const float*)d_in[1];
  const float* Wt   = (const float*)d_in[2];
  const float* bt   = (const float*)d_in[3];
  const float* gt   = (const float*)d_in[4];
  const float* bgt  = (const float*)d_in[5];
  const float* Wf   = (const float*)d_in[6];
  const float* bfv  = (const float*)d_in[7];
  const float* gf   = (const float*)d_in[8];
  const float* bgf  = (const float*)d_in[9];
  const float* Wo   = (const float*)d_in[10];
  const float* bo   = (const float*)d_in[11];
  const float* go   = (const float*)d_in[12];
  const float* bgo  = (const float*)d_in[13];

  float* tok = (float*)d_ws;            // 8 MB in ws
  float* out = (float*)d_out;

  hipLaunchKernelGGL(k_wintok, dim3(512), dim3(512), 0, stream,
                     h, Wt, bt, gt, bgt, tok);
  hipLaunchKernelGGL(k_fuse_out, dim3(512), dim3(512), 0, stream,
                     tok, Wf, bfv, gf, bgf, Wo, bo, go, bgo, mask, out);
}

// Round 9
// 97.356 us; speedup vs baseline: 1.3771x; 1.3771x over previous
//
#include <hip/hip_runtime.h>
#include <hip/hip_bf16.h>

// B=32, H=W=96, D=128, WS=6, SS=3.
// tok layout: [set(2)][b(32)][wy(16)][wx(16)][d(128)] = 8 MB in d_ws.
// k_wintok: unchanged from round 8 (window means via 3x3-tile sums + fused
// token_proj with LDS W half-panels).
// k_fuse_out: REWRITTEN with bf16 MFMA (32x32x16). Per block: xs bf16 in LDS,
// W staged transposed-bf16 (B-frag wants k-contig per out-col); LN/GELU as a
// separate pass through a raw-f32 LDS tile that overlays the dead W buffer.
// LDS 52.2 KB -> 3 blocks/CU.

#define DEVFN static __device__ __forceinline__

typedef __attribute__((ext_vector_type(8))) short bf16x8;
typedef __attribute__((ext_vector_type(16))) float f32x16;

DEVFN float gelu_exact(float x) {
  return 0.5f * x * (1.0f + erff(x * 0.70710678118654752f));
}

DEVFN unsigned short f2bf(float f) {  // RNE f32 -> bf16 bits (finite inputs)
  unsigned int u = __float_as_uint(f);
  u = (u + 0x7FFFu + ((u >> 16) & 1u)) >> 16;
  return (unsigned short)u;
}

DEVFN void add4(float4& a, const float4 v) {
  a.x += v.x; a.y += v.y; a.z += v.z; a.w += v.w;
}
DEVFN void fma4(float4& a, const float4 v, float m) {
  a.x = fmaf(v.x, m, a.x); a.y = fmaf(v.y, m, a.y);
  a.z = fmaf(v.z, m, a.z); a.w = fmaf(v.w, m, a.w);
}

// ---------------- fp32 GEMM helpers (used by k_wintok only) ----------------
DEVFN void stage_w(float (*wp)[128], const float* __restrict__ W, int krow0,
                   int tid) {
  const float4* src = reinterpret_cast<const float4*>(W + (size_t)krow0 * 128);
  #pragma unroll
  for (int i = 0; i < 4; ++i)
    reinterpret_cast<float4*>(&wp[0][0])[tid + i * 512] = src[tid + i * 512];
}

template <int T>
DEVFN void gemm_acc(const float (*wp)[128], const float (*xs)[128],
                    int kbase, int tb, int lane,
                    float (&a0)[T], float (&a1)[T]) {
  const int n0 = lane << 1;
  #pragma unroll 2
  for (int kk = 0; kk < 64; kk += 4) {
    const float2 w0 = *reinterpret_cast<const float2*>(&wp[kk + 0][n0]);
    const float2 w1 = *reinterpret_cast<const float2*>(&wp[kk + 1][n0]);
    const float2 w2 = *reinterpret_cast<const float2*>(&wp[kk + 2][n0]);
    const float2 w3 = *reinterpret_cast<const float2*>(&wp[kk + 3][n0]);
    #pragma unroll
    for (int t = 0; t < T; ++t) {
      const float4 xv =
          *reinterpret_cast<const float4*>(&xs[tb + t][kbase + kk]);
      a0[t] = fmaf(xv.x, w0.x, a0[t]); a1[t] = fmaf(xv.x, w0.y, a1[t]);
      a0[t] = fmaf(xv.y, w1.x, a0[t]); a1[t] = fmaf(xv.y, w1.y, a1[t]);
      a0[t] = fmaf(xv.z, w2.x, a0[t]); a1[t] = fmaf(xv.z, w2.y, a1[t]);
      a0[t] = fmaf(xv.w, w3.x, a0[t]); a1[t] = fmaf(xv.w, w3.y, a1[t]);
    }
  }
}

template <int T>
DEVFN void ln_gelu_finish(int lane, const float (&a0)[T], const float (&a1)[T],
                          const float* __restrict__ bias,
                          const float* __restrict__ gam,
                          const float* __restrict__ bet,
                          float (&o0)[T], float (&o1)[T]) {
  const int n0 = lane << 1;
  const float b0 = bias[n0], b1 = bias[n0 + 1];
  const float g0 = gam[n0],  g1 = gam[n0 + 1];
  const float e0 = bet[n0],  e1 = bet[n0 + 1];
  #pragma unroll
  for (int t = 0; t < T; ++t) {
    const float v0 = a0[t] + b0, v1 = a1[t] + b1;
    float s = v0 + v1, q = v0 * v0 + v1 * v1;
    #pragma unroll
    for (int m = 1; m < 64; m <<= 1) {
      s += __shfl_xor(s, m, 64);
      q += __shfl_xor(q, m, 64);
    }
    const float mean = s * (1.f / 128.f);
    const float var  = q * (1.f / 128.f) - mean * mean;
    const float inv  = rsqrtf(var + 1e-5f);
    o0[t] = gelu_exact((v0 - mean) * inv * g0 + e0);
    o1[t] = gelu_exact((v1 - mean) * inv * g1 + e1);
  }
}

// ------- Kernel 1: window means via 3x3-tile sums + fused token_proj -------
// (unchanged from round 8)
__global__ __launch_bounds__(512) void k_wintok(const float* __restrict__ h,
    const float* __restrict__ Wt, const float* __restrict__ bt,
    const float* __restrict__ gt, const float* __restrict__ bgt,
    float* __restrict__ tok) {
  __shared__ __align__(16) float tiles[3][32][128];
  const int b = blockIdx.x >> 4;
  const int r = blockIdx.x & 15;
  const int w    = threadIdx.x >> 6;      // wave 0..7
  const int lane = threadIdx.x & 63;
  const int half = lane >> 5;             // 0/1: which of the 2 cols per instr
  const int ch4  = (lane & 31) << 2;      // 4 channels per lane
  const float mlo = half ? 0.f : 1.f;
  const float mhi = 1.f - mlo;

  float4 acc[3][4];
  #pragma unroll
  for (int a = 0; a < 3; ++a)
    #pragma unroll
    for (int t = 0; t < 4; ++t) acc[a][t] = make_float4(0.f, 0.f, 0.f, 0.f);

  #pragma unroll
  for (int yl = 0; yl < 9; ++yl) {
    int y = 6 * r + yl; if (y >= 96) y -= 96;
    const int tr = yl / 3;                // static (unrolled)
    const float* rp =
        h + ((size_t)(b * 9216 + y * 96 + 12 * w + half) * 128 + ch4);
    #pragma unroll
    for (int j = 0; j < 6; ++j) {
      const float4 v = *reinterpret_cast<const float4*>(rp + j * 256);
      if (j == 0)      add4(acc[tr][0], v);
      else if (j == 2) add4(acc[tr][1], v);
      else if (j == 3) add4(acc[tr][2], v);
      else if (j == 5) add4(acc[tr][3], v);
      else if (j == 1) { fma4(acc[tr][0], v, mlo); fma4(acc[tr][1], v, mhi); }
      else             { fma4(acc[tr][2], v, mlo); fma4(acc[tr][3], v, mhi); }
    }
  }

  #pragma unroll
  for (int a = 0; a < 3; ++a)
    #pragma unroll
    for (int t = 0; t < 4; ++t) {
      float4 s = acc[a][t];
      s.x += __shfl_xor(s.x, 32, 64);
      s.y += __shfl_xor(s.y, 32, 64);
      s.z += __shfl_xor(s.z, 32, 64);
      s.w += __shfl_xor(s.w, 32, 64);
      if (half == 0)
        *reinterpret_cast<float4*>(&tiles[a][4 * w + t][ch4]) = s;
    }
  __syncthreads();

  float cv[8];
  #pragma unroll
  for (int j = 0; j < 8; ++j) {
    const int i = threadIdx.x + j * 512;   // 0..4095
    const int t = i >> 7, d = i & 127;
    if (t < 16) {
      const int wx = t;
      cv[j] = (tiles[0][2 * wx][d] + tiles[0][2 * wx + 1][d] +
               tiles[1][2 * wx][d] + tiles[1][2 * wx + 1][d]) * (1.f / 36.f);
    } else {
      const int wx = t - 16;
      const int cA = 2 * wx + 1, cB = (2 * wx + 2) & 31;
      cv[j] = (tiles[1][cA][d] + tiles[1][cB][d] +
               tiles[2][cA][d] + tiles[2][cB][d]) * (1.f / 36.f);
    }
  }
  __syncthreads();
  float (*xs)[128] = tiles[0];
  float (*wp)[128] = tiles[1];
  #pragma unroll
  for (int j = 0; j < 8; ++j) {
    const int i = threadIdx.x + j * 512;
    xs[i >> 7][i & 127] = cv[j];
  }
  stage_w(wp, Wt, 0, threadIdx.x);
  __syncthreads();

  const int tb = w * 4;
  float a0[4], a1[4];
  #pragma unroll
  for (int t = 0; t < 4; ++t) { a0[t] = 0.f; a1[t] = 0.f; }
  gemm_acc<4>(wp, xs, 0, tb, lane, a0, a1);
  __syncthreads();
  stage_w(wp, Wt, 64, threadIdx.x);
  __syncthreads();
  gemm_acc<4>(wp, xs, 64, tb, lane, a0, a1);
  float o0[4], o1[4];
  ln_gelu_finish<4>(lane, a0, a1, bt, gt, bgt, o0, o1);

  const int n0 = lane << 1;
  #pragma unroll
  for (int t = 0; t < 4; ++t) {
    const int tt = tb + t;
    const int s = tt >> 4, wx = tt & 15;
    *reinterpret_cast<float2*>(tok + (size_t)s * 1048576 +
        ((size_t)b * 16 + r) * 2048 + (size_t)wx * 128 + n0) =
        make_float2(o0[t], o1[t]);
  }
}

// ---------------- MFMA helpers for k_fuse_out ----------------
// Stage W (f32 global, [k][n]) -> transposed bf16 LDS Wl[n][k], rows padded
// to 136 elems (272 B, 16B-aligned) for conflict-free b128 frag reads.
DEVFN void stage_w_bf(unsigned short* __restrict__ wl,
                      const float* __restrict__ W, int tid) {
  #pragma unroll
  for (int p = 0; p < 4; ++p) {
    const int i = tid + p * 512;            // 0..2047: kpair x n4-chunk
    const int kp = i >> 5;                  // k pair index 0..63
    const int n4 = (i & 31) * 4;            // coalesced global float4 reads
    const float4 r0 = *reinterpret_cast<const float4*>(W + (size_t)(2 * kp) * 128 + n4);
    const float4 r1 = *reinterpret_cast<const float4*>(W + (size_t)(2 * kp + 1) * 128 + n4);
    const float a0[4] = {r0.x, r0.y, r0.z, r0.w};
    const float a1[4] = {r1.x, r1.y, r1.z, r1.w};
    #pragma unroll
    for (int j = 0; j < 4; ++j) {
      const unsigned int pk =
          (unsigned int)f2bf(a0[j]) | ((unsigned int)f2bf(a1[j]) << 16);
      *reinterpret_cast<unsigned int*>(&wl[(n4 + j) * 136 + 2 * kp]) = pk;
    }
  }
}

// 32x32 output tile per wave via 8x mfma_f32_32x32x16_bf16 over K=128.
// A: lane m=l&31 (token), k = kk*16 + 8*(l>>5) + j ; B: lane n=l&31 (outcol).
DEVFN f32x16 mfma_tile(const unsigned short* __restrict__ xrow,
                       const unsigned short* __restrict__ wrow) {
  f32x16 acc;
  #pragma unroll
  for (int r = 0; r < 16; ++r) acc[r] = 0.f;
  #pragma unroll
  for (int kk = 0; kk < 8; ++kk) {
    const bf16x8 a = *reinterpret_cast<const bf16x8*>(xrow + kk * 16);
    const bf16x8 bb = *reinterpret_cast<const bf16x8*>(wrow + kk * 16);
    acc = __builtin_amdgcn_mfma_f32_32x32x16_bf16(a, bb, acc, 0, 0, 0);
  }
  return acc;
}

// Scatter D-frags to raw f32 [64][132] (pad 132 -> conflict-free b32 writes).
// C/D layout (verified m74/m101): col = lane&31, row = (r&3)+8*(r>>2)+4*(l>>5).
DEVFN void write_raw(float* __restrict__ raw, const f32x16 acc,
                     int tg, int cg, int lane) {
  const int n  = cg * 32 + (lane & 31);
  const int mb = tg * 32 + 4 * (lane >> 5);
  #pragma unroll
  for (int r = 0; r < 16; ++r) {
    const int mm = mb + (r & 3) + 8 * (r >> 2);
    raw[mm * 132 + n] = acc[r];
  }
}

// -------- Kernel 2: fuse + out_proj via bf16 MFMA + expand --------
// grid = 32*16 (b, m), 512 threads = 8 waves; 64 tokens/block.
// Wave (tg = w>>2, cg = w&3) owns the 32-token x 32-col tile.
__global__ __launch_bounds__(512) void k_fuse_out(const float* __restrict__ tok,
    const float* __restrict__ Wf, const float* __restrict__ bfv,
    const float* __restrict__ gf, const float* __restrict__ bgf,
    const float* __restrict__ Wo, const float* __restrict__ bo,
    const float* __restrict__ go, const float* __restrict__ bgo,
    const float* __restrict__ mask, float* __restrict__ out) {
  __shared__ __align__(16) unsigned short xs_bf[64 * 136];   // 17408 B
  __shared__ __align__(16) unsigned short wl[128 * 136];     // 34816 B
  float* raw = reinterpret_cast<float*>(wl);                 // [64][132] f32

  const int tid = threadIdx.x;
  const int b = blockIdx.x >> 4;
  const int m = blockIdx.x & 15;
  const int lane = tid & 63;
  const int w = tid >> 6;
  const int tg = w >> 2, cg = w & 3;

  const float* tokR = tok + (size_t)b * 32768 + (size_t)m * 2048;
  const float* tokS = tok + 1048576 + (size_t)b * 32768;

  // Phase 0: gather reg+sh -> bf16 xs ; stage Wf transposed-bf16.
  #pragma unroll
  for (int p = 0; p < 2; ++p) {
    const int i = tid + p * 512;          // 64 rows x 16 chunks of 8 cols
    const int t = i >> 4, c8 = (i & 15) * 8;
    const int gx = t & 31, gy = 2 * m + (t >> 5);
    const int wx  = gx >> 1;
    const int wxs = ((gx + 31) & 31) >> 1;
    const int wys = ((gy + 31) & 31) >> 1;
    const float* pr = tokR + (size_t)wx * 128 + c8;
    const float* ps = tokS + (size_t)(wys * 16 + wxs) * 128 + c8;
    bf16x8 pk;
    #pragma unroll
    for (int j = 0; j < 8; ++j)
      pk[j] = (short)f2bf(pr[j] + ps[j]);
    *reinterpret_cast<bf16x8*>(&xs_bf[t * 136 + c8]) = pk;
  }
  stage_w_bf(wl, Wf, tid);
  __syncthreads();

  const unsigned short* xrow = &xs_bf[(tg * 32 + (lane & 31)) * 136 + 8 * (lane >> 5)];
  const unsigned short* wrow = &wl[(cg * 32 + (lane & 31)) * 136 + 8 * (lane >> 5)];

  // Phase 1: fuse GEMM.
  const f32x16 acc1 = mfma_tile(xrow, wrow);
  __syncthreads();                        // all wl reads done before raw write
  write_raw(raw, acc1, tg, cg, lane);
  __syncthreads();

  // Phase 3: LN+GELU(ctx) -> bf16 back into xs_bf. 8 threads/token.
  {
    const int tt = tid >> 3, cb = tid & 7;
    float v[16];
    float s = 0.f, q = 0.f;
    #pragma unroll
    for (int i = 0; i < 4; ++i) {
      const int col = 4 * cb + 32 * i;
      const float4 rv = *reinterpret_cast<const float4*>(&raw[tt * 132 + col]);
      const float4 bv = *reinterpret_cast<const float4*>(bfv + col);
      v[4 * i + 0] = rv.x + bv.x; v[4 * i + 1] = rv.y + bv.y;
      v[4 * i + 2] = rv.z + bv.z; v[4 * i + 3] = rv.w + bv.w;
    }
    #pragma unroll
    for (int e = 0; e < 16; ++e) { s += v[e]; q += v[e] * v[e]; }
    s += __shfl_xor(s, 1, 8); q += __shfl_xor(q, 1, 8);
    s += __shfl_xor(s, 2, 8); q += __shfl_xor(q, 2, 8);
    s += __shfl_xor(s, 4, 8); q += __shfl_xor(q, 4, 8);
    const float mean = s * (1.f / 128.f);
    const float var  = q * (1.f / 128.f) - mean * mean;
    const float inv  = rsqrtf(var + 1e-5f);
    __syncthreads();                      // raw fully read before Wo overwrites
    #pragma unroll
    for (int i = 0; i < 4; ++i) {
      const int col = 4 * cb + 32 * i;
      const float4 gv = *reinterpret_cast<const float4*>(gf + col);
      const float4 ev = *reinterpret_cast<const float4*>(bgf + col);
      short4 pk;
      pk.x = (short)f2bf(gelu_exact((v[4 * i + 0] - mean) * inv * gv.x + ev.x));
      pk.y = (short)f2bf(gelu_exact((v[4 * i + 1] - mean) * inv * gv.y + ev.y));
      pk.z = (short)f2bf(gelu_exact((v[4 * i + 2] - mean) * inv * gv.z + ev.z));
      pk.w = (short)f2bf(gelu_exact((v[4 * i + 3] - mean) * inv * gv.w + ev.w));
      *reinterpret_cast<short4*>(&xs_bf[tt * 136 + col]) = pk;
    }
  }
  __syncthreads();                        // xs ctx complete
  stage_w_bf(wl, Wo, tid);
  __syncthreads();

  // Phase 5: out_proj GEMM.
  const f32x16 acc2 = mfma_tile(xrow, wrow);
  __syncthreads();
  write_raw(raw, acc2, tg, cg, lane);
  __syncthreads();

  // Phase 7: LN+GELU(out) + mask + 3x3 expand stores (full-line coalesced).
  {
    const int tt = tid >> 3, cb = tid & 7;
    float v[16];
    float s = 0.f, q = 0.f;
    #pragma unroll
    for (int i = 0; i < 4; ++i) {
      const int col = 4 * cb + 32 * i;
      const float4 rv = *reinterpret_cast<const float4*>(&raw[tt * 132 + col]);
      const float4 bv = *reinterpret_cast<const float4*>(bo + col);
      v[4 * i + 0] = rv.x + bv.x; v[4 * i + 1] = rv.y + bv.y;
      v[4 * i + 2] = rv.z + bv.z; v[4 * i + 3] = rv.w + bv.w;
    }
    #pragma unroll
    for (int e = 0; e < 16; ++e) { s += v[e]; q += v[e] * v[e]; }
    s += __shfl_xor(s, 1, 8); q += __shfl_xor(q, 1, 8);
    s += __shfl_xor(s, 2, 8); q += __shfl_xor(q, 2, 8);
    s += __shfl_xor(s, 4, 8); q += __shfl_xor(q, 4, 8);
    const float mean = s * (1.f / 128.f);
    const float var  = q * (1.f / 128.f) - mean * mean;
    const float inv  = rsqrtf(var + 1e-5f);
    #pragma unroll
    for (int i = 0; i < 4; ++i) {
      const int col = 4 * cb + 32 * i;
      const float4 gv = *reinterpret_cast<const float4*>(go + col);
      const float4 ev = *reinterpret_cast<const float4*>(bgo + col);
      v[4 * i + 0] = gelu_exact((v[4 * i + 0] - mean) * inv * gv.x + ev.x);
      v[4 * i + 1] = gelu_exact((v[4 * i + 1] - mean) * inv * gv.y + ev.y);
      v[4 * i + 2] = gelu_exact((v[4 * i + 2] - mean) * inv * gv.z + ev.z);
      v[4 * i + 3] = gelu_exact((v[4 * i + 3] - mean) * inv * gv.w + ev.w);
    }
    const int gx = tt & 31, gy = 2 * m + (tt >> 5);
    #pragma unroll
    for (int py = 0; py < 3; ++py) {
      const int y = 3 * gy + py;
      #pragma unroll
      for (int px = 0; px < 3; ++px) {
        const int x = 3 * gx + px;
        const size_t pix = (size_t)b * 9216 + (size_t)y * 96 + x;
        const float mv = mask[pix];
        #pragma unroll
        for (int i = 0; i < 4; ++i) {
          const int col = 4 * cb + 32 * i;
          *reinterpret_cast<float4*>(out + pix * 128 + col) =
              make_float4(v[4 * i + 0] * mv, v[4 * i + 1] * mv,
                          v[4 * i + 2] * mv, v[4 * i + 3] * mv);
        }
      }
    }
  }
}

extern "C" void kernel_launch(void* const* d_in, const int* in_sizes, int n_in,
                              void* d_out, int out_size, void* d_ws, size_t ws_size,
                              hipStream_t stream) {
  (void)in_sizes; (void)n_in; (void)out_size; (void)ws_size;
  const float* h    = (const float*)d_in[0];
  const float* mask = (const float*)d_in[1];
  const float* Wt   = (const float*)d_in[2];
  const float* bt   = (const float*)d_in[3];
  const float* gt   = (const float*)d_in[4];
  const float* bgt  = (const float*)d_in[5];
  const float* Wf   = (const float*)d_in[6];
  const float* bfv  = (const float*)d_in[7];
  const float* gf   = (const float*)d_in[8];
  const float* bgf  = (const float*)d_in[9];
  const float* Wo   = (const float*)d_in[10];
  const float* bo   = (const float*)d_in[11];
  const float* go   = (const float*)d_in[12];
  const float* bgo  = (const float*)d_in[13];

  float* tok = (float*)d_ws;            // 8 MB in ws
  float* out = (float*)d_out;

  hipLaunchKernelGGL(k_wintok, dim3(512), dim3(512), 0, stream,
                     h, Wt, bt, gt, bgt, tok);
  hipLaunchKernelGGL(k_fuse_out, dim3(512), dim3(512), 0, stream,
                     tok, Wf, bfv, gf, bgf, Wo, bo, go, bgo, mask, out);
}

// Round 11
// 91.566 us; speedup vs baseline: 1.4642x; 1.0632x over previous
//
#include <hip/hip_runtime.h>
#include <hip/hip_bf16.h>

// B=32, H=W=96, D=128, WS=6, SS=3.
// Pipeline:
//  k_tile3   : h (151 MB, read ONCE) -> 3x3-tile sums S3 bf16 [b][ry32][c32][d128] (8 MB, ws)
//  k_tok     : S3 -> window means (4 tiles each) -> token_proj (bf16 MFMA) -> tok f32 (8 MB, ws)
//  k_fuse_out: tok -> fuse + out_proj (bf16 MFMA) -> 3x3 expand -> out (verbatim round 9)
// Window decomposition: reg (wy,wx) = tiles {2wy,2wy+1}x{2wx,2wx+1};
// shifted = tiles {2wy+1,2wy+2 &31}x{2wx+1,2wx+2 &31}.
// S3 b-stride = 32*32*128 = 131072 elements.  (Round-4/10 bug: gather used
// 524288 -> b>=8 read zeros -> exactly-zero output for b>=8, absmax 4.822.)

#define DEVFN static __device__ __forceinline__

typedef __attribute__((ext_vector_type(8))) short bf16x8;
typedef __attribute__((ext_vector_type(16))) float f32x16;

DEVFN float gelu_exact(float x) {
  return 0.5f * x * (1.0f + erff(x * 0.70710678118654752f));
}

DEVFN unsigned short f2bf(float f) {  // RNE f32 -> bf16 bits (finite inputs)
  unsigned int u = __float_as_uint(f);
  u = (u + 0x7FFFu + ((u >> 16) & 1u)) >> 16;
  return (unsigned short)u;
}

DEVFN float bf2f(unsigned short u) {
  return __uint_as_float((unsigned int)u << 16);
}

DEVFN void add4(float4& a, const float4 v) {
  a.x += v.x; a.y += v.y; a.z += v.z; a.w += v.w;
}
DEVFN void fma4(float4& a, const float4 v, float m) {
  a.x = fmaf(v.x, m, a.x); a.y = fmaf(v.y, m, a.y);
  a.z = fmaf(v.z, m, a.z); a.w = fmaf(v.w, m, a.w);
}

// ---------------- Kernel 1: 3x3-tile sums, bf16 output ----------------
// grid = 32*32 (b, ry), 512 threads = 8 waves. Block reads pixel rows
// 3ry..3ry+2 (no halo -> each input byte read exactly once). Wave w owns
// cols [12w,12w+12) = tiles 4w..4w+3; lane: half=l>>5 picks col parity,
// (l&31)*4 = channel chunk; float4 loads; masked-FMA on straddling pairs.
__global__ __launch_bounds__(512) void k_tile3(const float* __restrict__ h,
                                               unsigned short* __restrict__ S3) {
  const int b  = blockIdx.x >> 5;
  const int ry = blockIdx.x & 31;
  const int w    = threadIdx.x >> 6;
  const int lane = threadIdx.x & 63;
  const int half = lane >> 5;
  const int ch4  = (lane & 31) << 2;
  const float mlo = half ? 0.f : 1.f;
  const float mhi = 1.f - mlo;

  float4 acc[4];
  #pragma unroll
  for (int t = 0; t < 4; ++t) acc[t] = make_float4(0.f, 0.f, 0.f, 0.f);

  #pragma unroll
  for (int yy = 0; yy < 3; ++yy) {
    const float* rp =
        h + ((size_t)(b * 9216 + (3 * ry + yy) * 96 + 12 * w + half) * 128 + ch4);
    #pragma unroll
    for (int j = 0; j < 6; ++j) {        // col = 12w + 2j + half
      const float4 v = *reinterpret_cast<const float4*>(rp + j * 256);
      if (j == 0)      add4(acc[0], v);
      else if (j == 2) add4(acc[1], v);
      else if (j == 3) add4(acc[2], v);
      else if (j == 5) add4(acc[3], v);
      else if (j == 1) { fma4(acc[0], v, mlo); fma4(acc[1], v, mhi); }
      else             { fma4(acc[2], v, mlo); fma4(acc[3], v, mhi); }
    }
  }

  #pragma unroll
  for (int t = 0; t < 4; ++t) {
    float4 s = acc[t];
    s.x += __shfl_xor(s.x, 32, 64);
    s.y += __shfl_xor(s.y, 32, 64);
    s.z += __shfl_xor(s.z, 32, 64);
    s.w += __shfl_xor(s.w, 32, 64);
    if (half == 0) {
      short4 pk;
      pk.x = (short)f2bf(s.x); pk.y = (short)f2bf(s.y);
      pk.z = (short)f2bf(s.z); pk.w = (short)f2bf(s.w);
      *reinterpret_cast<short4*>(
          &S3[((size_t)(b * 32 + ry) * 32 + 4 * w + t) * 128 + ch4]) = pk;
    }
  }
}

// ---------------- MFMA helpers (shared by k_tok / k_fuse_out) ----------------
// Stage W (f32 global, [k][n]) -> transposed bf16 LDS Wl[n][k], rows padded
// to 136 elems for conflict-free b128 frag reads.
DEVFN void stage_w_bf(unsigned short* __restrict__ wl,
                      const float* __restrict__ W, int tid) {
  #pragma unroll
  for (int p = 0; p < 4; ++p) {
    const int i = tid + p * 512;            // 0..2047: kpair x n4-chunk
    const int kp = i >> 5;                  // k pair index 0..63
    const int n4 = (i & 31) * 4;            // coalesced global float4 reads
    const float4 r0 = *reinterpret_cast<const float4*>(W + (size_t)(2 * kp) * 128 + n4);
    const float4 r1 = *reinterpret_cast<const float4*>(W + (size_t)(2 * kp + 1) * 128 + n4);
    const float a0[4] = {r0.x, r0.y, r0.z, r0.w};
    const float a1[4] = {r1.x, r1.y, r1.z, r1.w};
    #pragma unroll
    for (int j = 0; j < 4; ++j) {
      const unsigned int pk =
          (unsigned int)f2bf(a0[j]) | ((unsigned int)f2bf(a1[j]) << 16);
      *reinterpret_cast<unsigned int*>(&wl[(n4 + j) * 136 + 2 * kp]) = pk;
    }
  }
}

// 32x32 output tile per wave via 8x mfma_f32_32x32x16_bf16 over K=128.
DEVFN f32x16 mfma_tile(const unsigned short* __restrict__ xrow,
                       const unsigned short* __restrict__ wrow) {
  f32x16 acc;
  #pragma unroll
  for (int r = 0; r < 16; ++r) acc[r] = 0.f;
  #pragma unroll
  for (int kk = 0; kk < 8; ++kk) {
    const bf16x8 a = *reinterpret_cast<const bf16x8*>(xrow + kk * 16);
    const bf16x8 bb = *reinterpret_cast<const bf16x8*>(wrow + kk * 16);
    acc = __builtin_amdgcn_mfma_f32_32x32x16_bf16(a, bb, acc, 0, 0, 0);
  }
  return acc;
}

// Scatter D-frags to raw f32 [64][132] (pad 132 -> conflict-free b32 writes).
// C/D layout (verified m74/m101): col = lane&31, row = (r&3)+8*(r>>2)+4*(l>>5).
DEVFN void write_raw(float* __restrict__ raw, const f32x16 acc,
                     int tg, int cg, int lane) {
  const int n  = cg * 32 + (lane & 31);
  const int mb = tg * 32 + 4 * (lane >> 5);
  #pragma unroll
  for (int r = 0; r < 16; ++r) {
    const int mm = mb + (r & 3) + 8 * (r >> 2);
    raw[mm * 132 + n] = acc[r];
  }
}

// ---------------- Kernel 2: window gather + token_proj (bf16 MFMA) ----------
// grid = 256 (64 tokens/block), 512 threads = 8 waves.
__global__ __launch_bounds__(512) void k_tok(const unsigned short* __restrict__ S3,
    const float* __restrict__ Wt, const float* __restrict__ bt,
    const float* __restrict__ gt, const float* __restrict__ bgt,
    float* __restrict__ tok) {
  __shared__ __align__(16) unsigned short xs_bf[64 * 136];
  __shared__ __align__(16) unsigned short wl[128 * 136];
  float* raw = reinterpret_cast<float*>(wl);

  const int tid = threadIdx.x;
  const int t0 = blockIdx.x * 64;
  const int s  = t0 >> 13;               // token set (uniform per block)
  const int b  = (t0 >> 8) & 31;
  const int wyx = t0 & 255;

  const unsigned short* Sb = S3 + (size_t)b * 131072;   // b-stride 32*32*128
  #pragma unroll
  for (int p = 0; p < 2; ++p) {
    const int i = tid + p * 512;          // 64 tokens x 16 chunks of 8 ch
    const int tt = i >> 4, c8 = (i & 15) * 8;
    const int idx = wyx + tt;
    const int wy = idx >> 4, wx = idx & 15;
    int ry0, ry1, c0, c1;
    if (s == 0) { ry0 = 2 * wy;     ry1 = 2 * wy + 1;        c0 = 2 * wx;     c1 = 2 * wx + 1; }
    else        { ry0 = 2 * wy + 1; ry1 = (2 * wy + 2) & 31; c0 = 2 * wx + 1; c1 = (2 * wx + 2) & 31; }
    const bf16x8 v00 = *reinterpret_cast<const bf16x8*>(Sb + ((size_t)(ry0 * 32 + c0) * 128 + c8));
    const bf16x8 v01 = *reinterpret_cast<const bf16x8*>(Sb + ((size_t)(ry0 * 32 + c1) * 128 + c8));
    const bf16x8 v10 = *reinterpret_cast<const bf16x8*>(Sb + ((size_t)(ry1 * 32 + c0) * 128 + c8));
    const bf16x8 v11 = *reinterpret_cast<const bf16x8*>(Sb + ((size_t)(ry1 * 32 + c1) * 128 + c8));
    bf16x8 pk;
    #pragma unroll
    for (int j = 0; j < 8; ++j) {
      const float sum = bf2f((unsigned short)v00[j]) + bf2f((unsigned short)v01[j]) +
                        bf2f((unsigned short)v10[j]) + bf2f((unsigned short)v11[j]);
      pk[j] = (short)f2bf(sum * (1.f / 36.f));
    }
    *reinterpret_cast<bf16x8*>(&xs_bf[tt * 136 + c8]) = pk;
  }
  stage_w_bf(wl, Wt, tid);
  __syncthreads();

  const int lane = tid & 63;
  const int w = tid >> 6;
  const int tg = w >> 2, cg = w & 3;
  const unsigned short* xrow = &xs_bf[(tg * 32 + (lane & 31)) * 136 + 8 * (lane >> 5)];
  const unsigned short* wrow = &wl[(cg * 32 + (lane & 31)) * 136 + 8 * (lane >> 5)];

  const f32x16 acc = mfma_tile(xrow, wrow);
  __syncthreads();
  write_raw(raw, acc, tg, cg, lane);
  __syncthreads();

  // LN+GELU -> tok f32. 8 threads/token.
  {
    const int tt = tid >> 3, cb = tid & 7;
    float v[16];
    float s2 = 0.f, q = 0.f;
    #pragma unroll
    for (int i = 0; i < 4; ++i) {
      const int col = 4 * cb + 32 * i;
      const float4 rv = *reinterpret_cast<const float4*>(&raw[tt * 132 + col]);
      const float4 bv = *reinterpret_cast<const float4*>(bt + col);
      v[4 * i + 0] = rv.x + bv.x; v[4 * i + 1] = rv.y + bv.y;
      v[4 * i + 2] = rv.z + bv.z; v[4 * i + 3] = rv.w + bv.w;
    }
    #pragma unroll
    for (int e = 0; e < 16; ++e) { s2 += v[e]; q += v[e] * v[e]; }
    s2 += __shfl_xor(s2, 1, 8); q += __shfl_xor(q, 1, 8);
    s2 += __shfl_xor(s2, 2, 8); q += __shfl_xor(q, 2, 8);
    s2 += __shfl_xor(s2, 4, 8); q += __shfl_xor(q, 4, 8);
    const float mean = s2 * (1.f / 128.f);
    const float var  = q * (1.f / 128.f) - mean * mean;
    const float inv  = rsqrtf(var + 1e-5f);
    #pragma unroll
    for (int i = 0; i < 4; ++i) {
      const int col = 4 * cb + 32 * i;
      const float4 gv = *reinterpret_cast<const float4*>(gt + col);
      const float4 ev = *reinterpret_cast<const float4*>(bgt + col);
      float4 ov;
      ov.x = gelu_exact((v[4 * i + 0] - mean) * inv * gv.x + ev.x);
      ov.y = gelu_exact((v[4 * i + 1] - mean) * inv * gv.y + ev.y);
      ov.z = gelu_exact((v[4 * i + 2] - mean) * inv * gv.z + ev.z);
      ov.w = gelu_exact((v[4 * i + 3] - mean) * inv * gv.w + ev.w);
      *reinterpret_cast<float4*>(tok + (size_t)(t0 + tt) * 128 + col) = ov;
    }
  }
}

// -------- Kernel 3: fuse + out_proj via bf16 MFMA + expand (round 9) --------
__global__ __launch_bounds__(512) void k_fuse_out(const float* __restrict__ tok,
    const float* __restrict__ Wf, const float* __restrict__ bfv,
    const float* __restrict__ gf, const float* __restrict__ bgf,
    const float* __restrict__ Wo, const float* __restrict__ bo,
    const float* __restrict__ go, const float* __restrict__ bgo,
    const float* __restrict__ mask, float* __restrict__ out) {
  __shared__ __align__(16) unsigned short xs_bf[64 * 136];   // 17408 B
  __shared__ __align__(16) unsigned short wl[128 * 136];     // 34816 B
  float* raw = reinterpret_cast<float*>(wl);                 // [64][132] f32

  const int tid = threadIdx.x;
  const int b = blockIdx.x >> 4;
  const int m = blockIdx.x & 15;
  const int lane = tid & 63;
  const int w = tid >> 6;
  const int tg = w >> 2, cg = w & 3;

  const float* tokR = tok + (size_t)b * 32768 + (size_t)m * 2048;
  const float* tokS = tok + 1048576 + (size_t)b * 32768;

  // Phase 0: gather reg+sh -> bf16 xs ; stage Wf transposed-bf16.
  #pragma unroll
  for (int p = 0; p < 2; ++p) {
    const int i = tid + p * 512;          // 64 rows x 16 chunks of 8 cols
    const int t = i >> 4, c8 = (i & 15) * 8;
    const int gx = t & 31, gy = 2 * m + (t >> 5);
    const int wx  = gx >> 1;
    const int wxs = ((gx + 31) & 31) >> 1;
    const int wys = ((gy + 31) & 31) >> 1;
    const float* pr = tokR + (size_t)wx * 128 + c8;
    const float* ps = tokS + (size_t)(wys * 16 + wxs) * 128 + c8;
    bf16x8 pk;
    #pragma unroll
    for (int j = 0; j < 8; ++j)
      pk[j] = (short)f2bf(pr[j] + ps[j]);
    *reinterpret_cast<bf16x8*>(&xs_bf[t * 136 + c8]) = pk;
  }
  stage_w_bf(wl, Wf, tid);
  __syncthreads();

  const unsigned short* xrow = &xs_bf[(tg * 32 + (lane & 31)) * 136 + 8 * (lane >> 5)];
  const unsigned short* wrow = &wl[(cg * 32 + (lane & 31)) * 136 + 8 * (lane >> 5)];

  // Phase 1: fuse GEMM.
  const f32x16 acc1 = mfma_tile(xrow, wrow);
  __syncthreads();                        // all wl reads done before raw write
  write_raw(raw, acc1, tg, cg, lane);
  __syncthreads();

  // Phase 3: LN+GELU(ctx) -> bf16 back into xs_bf. 8 threads/token.
  {
    const int tt = tid >> 3, cb = tid & 7;
    float v[16];
    float s = 0.f, q = 0.f;
    #pragma unroll
    for (int i = 0; i < 4; ++i) {
      const int col = 4 * cb + 32 * i;
      const float4 rv = *reinterpret_cast<const float4*>(&raw[tt * 132 + col]);
      const float4 bv = *reinterpret_cast<const float4*>(bfv + col);
      v[4 * i + 0] = rv.x + bv.x; v[4 * i + 1] = rv.y + bv.y;
      v[4 * i + 2] = rv.z + bv.z; v[4 * i + 3] = rv.w + bv.w;
    }
    #pragma unroll
    for (int e = 0; e < 16; ++e) { s += v[e]; q += v[e] * v[e]; }
    s += __shfl_xor(s, 1, 8); q += __shfl_xor(q, 1, 8);
    s += __shfl_xor(s, 2, 8); q += __shfl_xor(q, 2, 8);
    s += __shfl_xor(s, 4, 8); q += __shfl_xor(q, 4, 8);
    const float mean = s * (1.f / 128.f);
    const float var  = q * (1.f / 128.f) - mean * mean;
    const float inv  = rsqrtf(var + 1e-5f);
    __syncthreads();                      // raw fully read before Wo overwrites
    #pragma unroll
    for (int i = 0; i < 4; ++i) {
      const int col = 4 * cb + 32 * i;
      const float4 gv = *reinterpret_cast<const float4*>(gf + col);
      const float4 ev = *reinterpret_cast<const float4*>(bgf + col);
      short4 pk;
      pk.x = (short)f2bf(gelu_exact((v[4 * i + 0] - mean) * inv * gv.x + ev.x));
      pk.y = (short)f2bf(gelu_exact((v[4 * i + 1] - mean) * inv * gv.y + ev.y));
      pk.z = (short)f2bf(gelu_exact((v[4 * i + 2] - mean) * inv * gv.z + ev.z));
      pk.w = (short)f2bf(gelu_exact((v[4 * i + 3] - mean) * inv * gv.w + ev.w));
      *reinterpret_cast<short4*>(&xs_bf[tt * 136 + col]) = pk;
    }
  }
  __syncthreads();                        // xs ctx complete
  stage_w_bf(wl, Wo, tid);
  __syncthreads();

  // Phase 5: out_proj GEMM.
  const f32x16 acc2 = mfma_tile(xrow, wrow);
  __syncthreads();
  write_raw(raw, acc2, tg, cg, lane);
  __syncthreads();

  // Phase 7: LN+GELU(out) + mask + 3x3 expand stores (full-line coalesced).
  {
    const int tt = tid >> 3, cb = tid & 7;
    float v[16];
    float s = 0.f, q = 0.f;
    #pragma unroll
    for (int i = 0; i < 4; ++i) {
      const int col = 4 * cb + 32 * i;
      const float4 rv = *reinterpret_cast<const float4*>(&raw[tt * 132 + col]);
      const float4 bv = *reinterpret_cast<const float4*>(bo + col);
      v[4 * i + 0] = rv.x + bv.x; v[4 * i + 1] = rv.y + bv.y;
      v[4 * i + 2] = rv.z + bv.z; v[4 * i + 3] = rv.w + bv.w;
    }
    #pragma unroll
    for (int e = 0; e < 16; ++e) { s += v[e]; q += v[e] * v[e]; }
    s += __shfl_xor(s, 1, 8); q += __shfl_xor(q, 1, 8);
    s += __shfl_xor(s, 2, 8); q += __shfl_xor(q, 2, 8);
    s += __shfl_xor(s, 4, 8); q += __shfl_xor(q, 4, 8);
    const float mean = s * (1.f / 128.f);
    const float var  = q * (1.f / 128.f) - mean * mean;
    const float inv  = rsqrtf(var + 1e-5f);
    #pragma unroll
    for (int i = 0; i < 4; ++i) {
      const int col = 4 * cb + 32 * i;
      const float4 gv = *reinterpret_cast<const float4*>(go + col);
      const float4 ev = *reinterpret_cast<const float4*>(bgo + col);
      v[4 * i + 0] = gelu_exact((v[4 * i + 0] - mean) * inv * gv.x + ev.x);
      v[4 * i + 1] = gelu_exact((v[4 * i + 1] - mean) * inv * gv.y + ev.y);
      v[4 * i + 2] = gelu_exact((v[4 * i + 2] - mean) * inv * gv.z + ev.z);
      v[4 * i + 3] = gelu_exact((v[4 * i + 3] - mean) * inv * gv.w + ev.w);
    }
    const int gx = tt & 31, gy = 2 * m + (tt >> 5);
    #pragma unroll
    for (int py = 0; py < 3; ++py) {
      const int y = 3 * gy + py;
      #pragma unroll
      for (int px = 0; px < 3; ++px) {
        const int x = 3 * gx + px;
        const size_t pix = (size_t)b * 9216 + (size_t)y * 96 + x;
        const float mv = mask[pix];
        #pragma unroll
        for (int i = 0; i < 4; ++i) {
          const int col = 4 * cb + 32 * i;
          *reinterpret_cast<float4*>(out + pix * 128 + col) =
              make_float4(v[4 * i + 0] * mv, v[4 * i + 1] * mv,
                          v[4 * i + 2] * mv, v[4 * i + 3] * mv);
        }
      }
    }
  }
}

extern "C" void kernel_launch(void* const* d_in, const int* in_sizes, int n_in,
                              void* d_out, int out_size, void* d_ws, size_t ws_size,
                              hipStream_t stream) {
  (void)in_sizes; (void)n_in; (void)out_size; (void)ws_size;
  const float* h    = (const float*)d_in[0];
  const float* mask = (const float*)d_in[1];
  const float* Wt   = (const float*)d_in[2];
  const float* bt   = (const float*)d_in[3];
  const float* gt   = (const float*)d_in[4];
  const float* bgt  = (const float*)d_in[5];
  const float* Wf   = (const float*)d_in[6];
  const float* bfv  = (const float*)d_in[7];
  const float* gf   = (const float*)d_in[8];
  const float* bgf  = (const float*)d_in[9];
  const float* Wo   = (const float*)d_in[10];
  const float* bo   = (const float*)d_in[11];
  const float* go   = (const float*)d_in[12];
  const float* bgo  = (const float*)d_in[13];

  unsigned short* S3 = (unsigned short*)d_ws;                    // 8 MB
  float* tok = (float*)((char*)d_ws + (size_t)8 * 1024 * 1024);  // 8 MB
  float* out = (float*)d_out;

  hipLaunchKernelGGL(k_tile3, dim3(1024), dim3(512), 0, stream, h, S3);
  hipLaunchKernelGGL(k_tok, dim3(256), dim3(512), 0, stream,
                     S3, Wt, bt, gt, bgt, tok);
  hipLaunchKernelGGL(k_fuse_out, dim3(512), dim3(512), 0, stream,
                     tok, Wf, bfv, gf, bgf, Wo, bo, go, bgo, mask, out);
}